// Round 2
// baseline (3258.035 us; speedup 1.0000x reference)
//
#include <hip/hip_runtime.h>
#include <hip/hip_bf16.h>

// LSTM persistent-kernel for MI355X (gfx950), round 2 design.
//
// B=128, S=512, I=256, H=1024. The 512-step recurrence is strictly
// sequential -> one persistent kernel, 256 blocks (1/CU, co-resident),
// grid barrier per step, h exchanged through L3 with system-scope
// (sc0 sc1, L2-bypassing) atomics. NO cache invalidates anywhere, so x
// and W stay warm in L2.
//
// Partitioning (chosen to minimize h-broadcast traffic = #col-splits x h):
//   bid -> m = bid&3 (4 row-splits of 32 batch rows), n = bid>>2 (64
//   col-splits of 16 h-cols => 64 gate-cols i/f/g/o).
//   h traffic = 256 blocks x 64KB = 16 MB/step from L3 (~0.9us @ ~17TB/s).
//   Note bid%8 = XCD and m = (bid%8)&3 => same-XCD blocks share h rows
//   (sets up a future L2-cached-h + buffer_inv experiment).
//
// Waves: 8 = mw(2 M-tiles of 16 rows) x kh(4 K-quarters of 256).
// W_hh B-fragments are STEP-INVARIANT -> held in 128 VGPRs/lane for the
// whole kernel (no per-step LDS traffic for weights). W_ih in LDS.
// c-state lives in registers. Gate partials reduced across kh via LDS.

#define LSTM_H 1024
#define LSTM_I 256
#define LSTM_S 512
#define LSTM_B 128

typedef float  f32x4  __attribute__((ext_vector_type(4)));
typedef short  bf16x8 __attribute__((ext_vector_type(8)));

static __device__ __forceinline__ unsigned short f2bf(float f) {
    unsigned int u = __float_as_uint(f);
    u += 0x7fffu + ((u >> 16) & 1u);     // RNE
    return (unsigned short)(u >> 16);
}
static __device__ __forceinline__ float bf2f(unsigned short s) {
    return __uint_as_float(((unsigned int)s) << 16);
}
static __device__ __forceinline__ float sigm(float x) {
    return 1.f / (1.f + __expf(-x));                 // saturates safely
}
static __device__ __forceinline__ float tanh_fast(float x) {
    return 2.f / (1.f + __expf(-2.f * x)) - 1.f;     // overflow-safe
}

#define ALOAD64(p)     __hip_atomic_load((const unsigned long long*)(p), __ATOMIC_RELAXED, __HIP_MEMORY_SCOPE_SYSTEM)
#define ASTORE32(p, v) __hip_atomic_store((unsigned int*)(p), (v), __ATOMIC_RELAXED, __HIP_MEMORY_SCOPE_SYSTEM)

// -------------------- h0 -> bf16 init --------------------
__global__ void init_h(const float* __restrict__ h0, unsigned short* hbuf0) {
    int i = blockIdx.x * blockDim.x + threadIdx.x;   // over u32 pairs
    if (i < LSTM_B * LSTM_H / 2) {
        unsigned int packed = (unsigned int)f2bf(h0[2 * i]) |
                              ((unsigned int)f2bf(h0[2 * i + 1]) << 16);
        ASTORE32(((unsigned int*)hbuf0) + i, packed);  // L2-bypass: no stale lines
    }
}

// -------------------- persistent LSTM --------------------
__global__ __launch_bounds__(512, 2) void lstm_persist(
    const float* __restrict__ x,     // (B, S, I)
    const float* __restrict__ c0,    // (B, H)
    const float* __restrict__ W_ih,  // (4H, I)
    const float* __restrict__ W_hh,  // (4H, H)
    const float* __restrict__ b_ih,  // (4H)
    const float* __restrict__ b_hh,  // (4H)
    unsigned short* hbuf0, unsigned short* hbuf1,
    unsigned int* flags /* [256], memset 0 per launch */)
{
    // LDS: 33.8KB + 34.8KB = 68.6KB -> 1 block/CU (VGPR-limited anyway)
    __shared__ short w_ih[64][264];      // 64 gate-cols x 256 K, pad 8 (16B quads spread)
    __shared__ float gacc[4][32][68];    // kh-partials: 4 x 32 rows x 64 gate-cols (+4 pad)

    const int tid  = threadIdx.x;
    const int bid  = blockIdx.x;
    const int m    = bid & 3;            // row split
    const int n    = bid >> 2;           // col split
    const int row0 = m * 32;
    const int col0 = n * 16;

    const int lane = tid & 63;
    const int wid  = tid >> 6;           // 0..7
    const int mw   = wid & 1;            // M-tile (16 rows)
    const int kh   = wid >> 1;           // K-quarter (256)
    const int l15  = lane & 15;
    const int slot = lane >> 4;          // 0..3
    const int arow = row0 + mw * 16 + l15;

    // ---- stage W_ih slice to LDS (row c in [0,64): gate c>>4, h-col col0+(c&15)) ----
    for (int i = tid; i < 64 * 64; i += 512) {     // float4 units over (64 x 256)
        const int c = i >> 6, q = i & 63;
        const int grow = (c >> 4) * LSTM_H + col0 + (c & 15);
        float4 v = *((const float4*)(W_ih + (size_t)grow * LSTM_I) + q);
        short* dst = &w_ih[c][q * 4];
        dst[0] = (short)f2bf(v.x); dst[1] = (short)f2bf(v.y);
        dst[2] = (short)f2bf(v.z); dst[3] = (short)f2bf(v.w);
    }

    // ---- W_hh B-fragments -> REGISTERS (step-invariant; 128 VGPRs/lane) ----
    // B-frag for col-tile t (= gate t), k-chunk kk: lane holds
    // W_hh[t*H + col0 + l15][kh*256 + kk*32 + slot*8 + j], j=0..7.
    bf16x8 bw[8][4];
    #pragma unroll
    for (int kk = 0; kk < 8; ++kk) {
        #pragma unroll
        for (int t = 0; t < 4; ++t) {
            const float* p = W_hh + (size_t)(t * LSTM_H + col0 + l15) * LSTM_H
                           + kh * 256 + kk * 32 + slot * 8;
            float4 a = *(const float4*)p;
            float4 b = *(const float4*)(p + 4);
            union { bf16x8 v; unsigned short e[8]; } u;
            u.e[0] = f2bf(a.x); u.e[1] = f2bf(a.y); u.e[2] = f2bf(a.z); u.e[3] = f2bf(a.w);
            u.e[4] = f2bf(b.x); u.e[5] = f2bf(b.y); u.e[6] = f2bf(b.z); u.e[7] = f2bf(b.w);
            bw[kk][t] = u.v;
        }
    }

    // ---- cell-phase constants: thread -> (row 0..31, h-col 0..15) ----
    const int crow = tid >> 4;
    const int chc  = tid & 15;
    const int hcol = col0 + chc;
    float cstate = c0[(size_t)(row0 + crow) * LSTM_H + hcol];
    const float bi = b_ih[hcol]                + b_hh[hcol];
    const float bf = b_ih[LSTM_H + hcol]       + b_hh[LSTM_H + hcol];
    const float bg = b_ih[2 * LSTM_H + hcol]   + b_hh[2 * LSTM_H + hcol];
    const float bo = b_ih[3 * LSTM_H + hcol]   + b_hh[3 * LSTM_H + hcol];

    const float* xbase = x + (size_t)arow * (LSTM_S * LSTM_I);

    const unsigned short* hread  = hbuf0;
    unsigned short*       hwrite = hbuf1;

    __syncthreads();   // LDS weights ready

    for (int s = 0; s < LSTM_S; ++s) {
        f32x4 acc[4];
        #pragma unroll
        for (int t = 0; t < 4; ++t) acc[t] = (f32x4){0.f, 0.f, 0.f, 0.f};

        // ---- input projection (h-independent: hides under barrier skew) ----
        #pragma unroll
        for (int kk = 0; kk < 2; ++kk) {
            const int k0 = kh * 64 + kk * 32 + slot * 8;
            const float* xp = xbase + (size_t)s * LSTM_I + k0;
            float4 xa = *(const float4*)xp;
            float4 xb = *(const float4*)(xp + 4);
            union { bf16x8 v; unsigned short e[8]; } ux;
            ux.e[0] = f2bf(xa.x); ux.e[1] = f2bf(xa.y); ux.e[2] = f2bf(xa.z); ux.e[3] = f2bf(xa.w);
            ux.e[4] = f2bf(xb.x); ux.e[5] = f2bf(xb.y); ux.e[6] = f2bf(xb.z); ux.e[7] = f2bf(xb.w);
            #pragma unroll
            for (int t = 0; t < 4; ++t) {
                bf16x8 bv = *(const bf16x8*)&w_ih[t * 16 + l15][k0];
                acc[t] = __builtin_amdgcn_mfma_f32_16x16x32_bf16(ux.v, bv, acc[t], 0, 0, 0);
            }
        }

        // ---- flat grid barrier: wait until all 256 blocks stored h(s-1) ----
        // flags[j] = #steps block j completed; need all >= s (s=0: trivially true).
        if (wid == 0) {
            const unsigned long long* fp = ((const unsigned long long*)flags) + lane * 2;
            const unsigned g = (unsigned)s;
            int guard = 0;
            for (;;) {
                unsigned long long q0 = ALOAD64(fp);
                unsigned long long q1 = ALOAD64(fp + 1);
                int ok = ((unsigned)q0 >= g) & ((unsigned)(q0 >> 32) >= g) &
                         ((unsigned)q1 >= g) & ((unsigned)(q1 >> 32) >= g);
                if (__all(ok)) break;
                __builtin_amdgcn_s_sleep(2);
                if (++guard > (1 << 18)) break;   // fail-loud, never hang
            }
        }
        __syncthreads();
        asm volatile("" ::: "memory");   // no load hoisting above the barrier

        // ---- recurrent part: prefetch all A-frags (L3 latency pipelines), then MFMA ----
        const unsigned short* hr = hread + (size_t)arow * LSTM_H + kh * 256 + slot * 8;
        unsigned long long aq[8][2];
        #pragma unroll
        for (int kk = 0; kk < 8; ++kk) {
            aq[kk][0] = ALOAD64(hr + kk * 32);
            aq[kk][1] = ALOAD64(hr + kk * 32 + 4);
        }
        #pragma unroll
        for (int kk = 0; kk < 8; ++kk) {
            union { bf16x8 v; unsigned long long q[2]; } ua;
            ua.q[0] = aq[kk][0]; ua.q[1] = aq[kk][1];
            #pragma unroll
            for (int t = 0; t < 4; ++t)
                acc[t] = __builtin_amdgcn_mfma_f32_16x16x32_bf16(ua.v, bw[kk][t], acc[t], 0, 0, 0);
        }

        // ---- gate partials -> LDS (C/D: col=lane&15, row=(lane>>4)*4+r) ----
        #pragma unroll
        for (int t = 0; t < 4; ++t)
            #pragma unroll
            for (int r = 0; r < 4; ++r)
                gacc[kh][mw * 16 + slot * 4 + r][t * 16 + l15] = acc[t][r];
        __syncthreads();

        // ---- cell update: one thread per (row, h-col); sum 4 kh-partials ----
        {
            float gi = gacc[0][crow][chc]      + gacc[1][crow][chc]      +
                       gacc[2][crow][chc]      + gacc[3][crow][chc]      + bi;
            float gf = gacc[0][crow][16 + chc] + gacc[1][crow][16 + chc] +
                       gacc[2][crow][16 + chc] + gacc[3][crow][16 + chc] + bf;
            float gg = gacc[0][crow][32 + chc] + gacc[1][crow][32 + chc] +
                       gacc[2][crow][32 + chc] + gacc[3][crow][32 + chc] + bg;
            float go = gacc[0][crow][48 + chc] + gacc[1][crow][48 + chc] +
                       gacc[2][crow][48 + chc] + gacc[3][crow][48 + chc] + bo;
            float iv = sigm(gi), fv = sigm(gf), gv = tanh_fast(gg), ov = sigm(go);
            cstate = fv * cstate + iv * gv;
            float hnew = ov * tanh_fast(cstate);
            unsigned short hb = f2bf(hnew);
            int pv = __shfl_down((int)hb, 1);          // partner h-col (tid+1, same wave)
            if ((chc & 1) == 0) {
                unsigned int packed = (unsigned int)hb | ((unsigned int)pv << 16);
                ASTORE32(hwrite + (size_t)(row0 + crow) * LSTM_H + col0 + chc, packed);
            }
        }

        // ---- publish: syncthreads drains all waves' h-stores (vmcnt0) before flag ----
        __syncthreads();
        if (tid == 0) ASTORE32(&flags[bid], (unsigned)(s + 1));

        // ---- ping-pong ----
        const unsigned short* t2 = hread;
        hread = hwrite; hwrite = (unsigned short*)t2;
    }
}

// -------------------- output projection: out = h_last @ W_out^T + b_out --------------------
// Separate kernel: the kernel boundary gives device-wide visibility, plain loads OK.
__global__ void out_proj(const unsigned short* __restrict__ hbuf,
                         const float* __restrict__ W_out,
                         const float* __restrict__ b_out,
                         float* __restrict__ out) {
    const int gtid = blockIdx.x * 256 + threadIdx.x;
    const int wid  = gtid >> 6;              // 1280 waves: one per (b, c)
    const int lane = gtid & 63;
    const int b = wid / 10, c = wid % 10;
    const unsigned short* hr = hbuf + (size_t)b * LSTM_H;
    const float* wr = W_out + (size_t)c * LSTM_H;
    float sum = 0.f;
    #pragma unroll
    for (int k4 = 0; k4 < 4; ++k4) {         // lane covers 4 groups of 4 bf16
        const int kb = (k4 * 64 + lane) * 4;
        unsigned long long q = *(const unsigned long long*)(hr + kb);
        #pragma unroll
        for (int j = 0; j < 4; ++j)
            sum += bf2f((unsigned short)(q >> (16 * j))) * wr[kb + j];
    }
    #pragma unroll
    for (int off = 32; off > 0; off >>= 1) sum += __shfl_down(sum, off);
    if (lane == 0) out[b * 10 + c] = sum + b_out[c];
}

// -------------------- launch --------------------
extern "C" void kernel_launch(void* const* d_in, const int* in_sizes, int n_in,
                              void* d_out, int out_size, void* d_ws, size_t ws_size,
                              hipStream_t stream) {
    const float* x     = (const float*)d_in[0];
    const float* h0    = (const float*)d_in[1];
    const float* c0    = (const float*)d_in[2];
    const float* W_ih  = (const float*)d_in[3];
    const float* W_hh  = (const float*)d_in[4];
    const float* b_ih  = (const float*)d_in[5];
    const float* b_hh  = (const float*)d_in[6];
    const float* W_out = (const float*)d_in[7];
    const float* b_out = (const float*)d_in[8];
    float* out = (float*)d_out;

    // ws layout: hbuf0 (256KB) | hbuf1 (256KB) | flags (256 u32)
    unsigned short* hbuf0 = (unsigned short*)d_ws;
    unsigned short* hbuf1 = hbuf0 + LSTM_B * LSTM_H;
    unsigned int*   flags = (unsigned int*)((char*)d_ws + 2 * (size_t)LSTM_B * LSTM_H * 2);

    hipMemsetAsync(flags, 0, 1024, stream);
    hipLaunchKernelGGL(init_h, dim3(256), dim3(256), 0, stream, h0, hbuf0);
    hipLaunchKernelGGL(lstm_persist, dim3(256), dim3(512), 0, stream,
                       x, c0, W_ih, W_hh, b_ih, b_hh, hbuf0, hbuf1, flags);
    // 512 steps (even) -> final h is in hbuf0 (s=511 writes hbuf0)
    hipLaunchKernelGGL(out_proj, dim3(320), dim3(256), 0, stream, hbuf0, W_out, b_out, out);
}